// Round 1
// baseline (204.843 us; speedup 1.0000x reference)
//
#include <hip/hip_runtime.h>
#include <hip/hip_bf16.h>

#define EPSF 1e-6f
#define Bsz 2
#define Tn  512
#define En  1024
#define Hn  256

// ---------------------------------------------------------------------------
// block-wide (256-thread) sum reduction, result broadcast to all threads
// ---------------------------------------------------------------------------
__device__ __forceinline__ float block_reduce_sum_256(float v, float* smem) {
  #pragma unroll
  for (int off = 32; off > 0; off >>= 1) v += __shfl_down(v, off, 64);
  const int wave = threadIdx.x >> 6;
  const int lane = threadIdx.x & 63;
  if (lane == 0) smem[wave] = v;
  __syncthreads();
  float s = smem[0] + smem[1] + smem[2] + smem[3];
  __syncthreads();
  return s;
}

// ---------------------------------------------------------------------------
// K1: r = RMSNorm(x) ; a = RMSNorm(r@w1 + b1) ; b = RMSNorm(r@w2 + b2)
// One block handles R_AB rows for ONE of the two weight matrices
// (blockIdx.x & 1 selects w1 vs w2) -> 256 blocks total, good occupancy.
// normalize(x)@w == rowscale * (x@w)  (rowscale folded in after GEMM).
// ---------------------------------------------------------------------------
#define R_AB 8
__global__ __launch_bounds__(256) void k_norm_gemm_ab(
    const float* __restrict__ x,
    const float* __restrict__ w1, const float* __restrict__ b1,
    const float* __restrict__ w2, const float* __restrict__ b2,
    float* __restrict__ A, float* __restrict__ Bm)
{
  const int which  = blockIdx.x & 1;        // 0 -> (w1,b1,A), 1 -> (w2,b2,Bm)
  const int rowblk = blockIdx.x >> 1;       // 0..127
  const int row0   = rowblk * R_AB;
  const int h      = threadIdx.x;           // 0..255 (output col)

  const float* __restrict__ w    = which ? w2 : w1;
  const float* __restrict__ bias = which ? b2 : b1;
  float*       __restrict__ outp = which ? Bm : A;

  __shared__ float xs[R_AB][En];            // 32 KB
  __shared__ float red[4];
  __shared__ float rowscale[R_AB];

  // stage 8 x-rows into LDS (float4 per thread per row)
  #pragma unroll
  for (int r = 0; r < R_AB; ++r) {
    float4 v = ((const float4*)(x + (size_t)(row0 + r) * En))[h];
    ((float4*)&xs[r][0])[h] = v;
  }
  __syncthreads();

  // per-row sum of squares -> rms scale
  for (int r = 0; r < R_AB; ++r) {
    float4 v = ((const float4*)&xs[r][0])[h];
    float ss = v.x*v.x + v.y*v.y + v.z*v.z + v.w*v.w;
    ss = block_reduce_sum_256(ss, red);
    if (h == 0) rowscale[r] = rsqrtf(ss * (1.0f / En) + EPSF);
  }
  __syncthreads();

  // GEMM: acc[r] = x_row[r] . w[:,h]
  float acc[R_AB];
  #pragma unroll
  for (int r = 0; r < R_AB; ++r) acc[r] = 0.f;

  for (int k = 0; k < En; k += 4) {
    float4 xv[R_AB];
    #pragma unroll
    for (int r = 0; r < R_AB; ++r) xv[r] = *(const float4*)&xs[r][k];
    #pragma unroll
    for (int kk = 0; kk < 4; ++kk) {
      float wv = w[(size_t)(k + kk) * Hn + h];
      #pragma unroll
      for (int r = 0; r < R_AB; ++r) {
        float xe = (kk == 0) ? xv[r].x : (kk == 1) ? xv[r].y
                 : (kk == 2) ? xv[r].z : xv[r].w;
        acc[r] = fmaf(xe, wv, acc[r]);
      }
    }
  }

  // fold in row rms scale, add bias, RMSNorm over h, store
  const float bv = bias[h];
  #pragma unroll
  for (int r = 0; r < R_AB; ++r) {
    float val = acc[r] * rowscale[r] + bv;
    float ss  = block_reduce_sum_256(val * val, red);
    float sc  = rsqrtf(ss * (1.0f / Hn) + EPSF);
    outp[(size_t)(row0 + r) * Hn + h] = val * sc;
  }
}

// ---------------------------------------------------------------------------
// K2: y[i,h] = (1/(i+1)) * sum_{j<=i} relu(a[i,h] + b[j,h]);  y = RMSNorm(y)
// ITILE=4 rows i per block; thread = h. b[j,:] loads are coalesced (1KB/iter)
// and L2-resident.
// ---------------------------------------------------------------------------
#define ITILE 4
__global__ __launch_bounds__(256) void k_bar(
    const float* __restrict__ A, const float* __restrict__ Bm,
    float* __restrict__ Y)
{
  const int tile = blockIdx.x & ((Tn / ITILE) - 1);  // 0..127
  const int bb   = blockIdx.x >> 7;                  // batch
  const int i0   = tile * ITILE;
  const int h    = threadIdx.x;
  const size_t base = (size_t)bb * Tn * Hn;

  float av[ITILE], sum[ITILE];
  #pragma unroll
  for (int r = 0; r < ITILE; ++r) {
    av[r]  = A[base + (size_t)(i0 + r) * Hn + h];
    sum[r] = 0.f;
  }

  const float* __restrict__ bp = Bm + base + h;
  // j < i0 : all ITILE rows active (no predication)
  for (int j = 0; j < i0; ++j) {
    float bv = bp[(size_t)j * Hn];
    #pragma unroll
    for (int r = 0; r < ITILE; ++r) sum[r] += fmaxf(av[r] + bv, 0.f);
  }
  // tail: j in [i0, i0+ITILE), row r active iff j <= i0+r
  #pragma unroll
  for (int t = 0; t < ITILE; ++t) {
    float bv = bp[(size_t)(i0 + t) * Hn];
    #pragma unroll
    for (int r = t; r < ITILE; ++r) sum[r] += fmaxf(av[r] + bv, 0.f);
  }

  __shared__ float red[4];
  #pragma unroll
  for (int r = 0; r < ITILE; ++r) {
    float y  = sum[r] / (float)(i0 + r + 1);
    float ss = block_reduce_sum_256(y * y, red);
    float sc = rsqrtf(ss * (1.0f / Hn) + EPSF);
    Y[base + (size_t)(i0 + r) * Hn + h] = y * sc;
  }
}

// ---------------------------------------------------------------------------
// K3: out = x + Y @ w3 + b3.  R3=4 rows/block; thread owns 4 consecutive
// output cols (float4 on w3 / x / out).
// ---------------------------------------------------------------------------
#define R3 4
__global__ __launch_bounds__(256) void k_gemm_out(
    const float* __restrict__ Y,
    const float* __restrict__ w3, const float* __restrict__ b3,
    const float* __restrict__ x, float* __restrict__ out)
{
  const int row0 = blockIdx.x * R3;
  const int h    = threadIdx.x;   // col group: e = 4h..4h+3

  __shared__ float ys[R3][Hn];    // 4 KB
  #pragma unroll
  for (int r = 0; r < R3; ++r)
    ys[r][h] = Y[(size_t)(row0 + r) * Hn + h];
  __syncthreads();

  float4 acc[R3];
  #pragma unroll
  for (int r = 0; r < R3; ++r) acc[r] = make_float4(0.f, 0.f, 0.f, 0.f);

  for (int k = 0; k < Hn; ++k) {
    float4 wv = *(const float4*)&w3[(size_t)k * En + h * 4];
    #pragma unroll
    for (int r = 0; r < R3; ++r) {
      float yv = ys[r][k];
      acc[r].x = fmaf(yv, wv.x, acc[r].x);
      acc[r].y = fmaf(yv, wv.y, acc[r].y);
      acc[r].z = fmaf(yv, wv.z, acc[r].z);
      acc[r].w = fmaf(yv, wv.w, acc[r].w);
    }
  }

  const float4 bvv = *(const float4*)&b3[h * 4];
  #pragma unroll
  for (int r = 0; r < R3; ++r) {
    float4 xv = *(const float4*)&x[(size_t)(row0 + r) * En + h * 4];
    float4 o;
    o.x = xv.x + acc[r].x + bvv.x;
    o.y = xv.y + acc[r].y + bvv.y;
    o.z = xv.z + acc[r].z + bvv.z;
    o.w = xv.w + acc[r].w + bvv.w;
    ((float4*)out)[(size_t)(row0 + r) * (En / 4) + h] = o;
  }
}

// ---------------------------------------------------------------------------
extern "C" void kernel_launch(void* const* d_in, const int* in_sizes, int n_in,
                              void* d_out, int out_size, void* d_ws, size_t ws_size,
                              hipStream_t stream) {
  const float* x  = (const float*)d_in[0];
  const float* w1 = (const float*)d_in[1];
  const float* b1 = (const float*)d_in[2];
  const float* w2 = (const float*)d_in[3];
  const float* b2 = (const float*)d_in[4];
  const float* w3 = (const float*)d_in[5];
  const float* b3 = (const float*)d_in[6];
  float* out = (float*)d_out;

  float* A  = (float*)d_ws;                       // [B*T, H]
  float* Bm = A  + (size_t)Bsz * Tn * Hn;         // [B*T, H]
  float* Y  = Bm + (size_t)Bsz * Tn * Hn;         // [B*T, H]

  k_norm_gemm_ab<<<(Bsz * Tn / R_AB) * 2, 256, 0, stream>>>(x, w1, b1, w2, b2, A, Bm);
  k_bar<<<Bsz * (Tn / ITILE), 256, 0, stream>>>(A, Bm, Y);
  k_gemm_out<<<Bsz * Tn / R3, 256, 0, stream>>>(Y, w3, b3, x, out);
}

// Round 2
// 78.357 us; speedup vs baseline: 2.6142x; 2.6142x over previous
//
#include <hip/hip_runtime.h>
#include <hip/hip_bf16.h>

#define EPSF 1e-6f
#define Bsz 2
#define Tn  512
#define En  1024
#define Hn  256
#define Mtot (Bsz * Tn)   // 1024 rows total

// ---------------------------------------------------------------------------
// float4 helpers
// ---------------------------------------------------------------------------
__device__ __forceinline__ float4 f4_fma(float s, float4 w, float4 a) {
  a.x = fmaf(s, w.x, a.x); a.y = fmaf(s, w.y, a.y);
  a.z = fmaf(s, w.z, a.z); a.w = fmaf(s, w.w, a.w);
  return a;
}

__device__ __forceinline__ float block_reduce_sum_256(float v, float* smem) {
  #pragma unroll
  for (int off = 32; off > 0; off >>= 1) v += __shfl_down(v, off, 64);
  const int wave = threadIdx.x >> 6;
  const int lane = threadIdx.x & 63;
  if (lane == 0) smem[wave] = v;
  __syncthreads();
  float s = smem[0] + smem[1] + smem[2] + smem[3];
  __syncthreads();
  return s;
}

// ---------------------------------------------------------------------------
// K0: rowscale_x[m] = rsqrt(mean(x[m,:]^2) + eps).  Wave per row.
// ---------------------------------------------------------------------------
__global__ __launch_bounds__(256) void k_rowscale(
    const float* __restrict__ x, float* __restrict__ rs)
{
  const int row  = blockIdx.x * 4 + (threadIdx.x >> 6);
  const int lane = threadIdx.x & 63;
  const float4* xp = (const float4*)(x + (size_t)row * En);
  float ss = 0.f;
  #pragma unroll
  for (int i = 0; i < 4; ++i) {
    float4 v = xp[lane + 64 * i];
    ss += v.x*v.x + v.y*v.y + v.z*v.z + v.w*v.w;
  }
  #pragma unroll
  for (int off = 32; off > 0; off >>= 1) ss += __shfl_down(ss, off, 64);
  if (lane == 0) rs[row] = rsqrtf(ss * (1.0f / En) + EPSF);
}

// ---------------------------------------------------------------------------
// K1: raw a/b GEMM, LDS-tiled. BM=32, BN=64, BK=32, 256 thr, micro 2x4.
// a_raw[m,n] = (x[m,:] . w[:,n]) * rowscale[m] + bias[n]
// grid: 32 mtiles * 4 ntiles * 2 which = 256 blocks
// ---------------------------------------------------------------------------
__global__ __launch_bounds__(256) void k_gemm_ab(
    const float* __restrict__ x,
    const float* __restrict__ w1, const float* __restrict__ b1,
    const float* __restrict__ w2, const float* __restrict__ b2,
    const float* __restrict__ rs,
    float* __restrict__ A, float* __restrict__ Bm)
{
  const int bx    = blockIdx.x;
  const int which = bx & 1;
  const int nt    = (bx >> 1) & 3;
  const int mt    = bx >> 3;
  const int m0 = mt * 32, n0 = nt * 64;
  const float* __restrict__ w    = which ? w2 : w1;
  const float* __restrict__ bias = which ? b2 : b1;
  float*       __restrict__ outp = which ? Bm : A;

  __shared__ float xs[32][36];   // +4 pad (16B-aligned rows)
  __shared__ float ws[32][64];

  const int t  = threadIdx.x;
  const int mr = (t >> 4) * 2;        // 0,2,...,30
  const int nc = (t & 15) * 4;        // 0,4,...,60

  float4 acc0 = make_float4(0,0,0,0), acc1 = make_float4(0,0,0,0);

  for (int k0 = 0; k0 < En; k0 += 32) {
    { // stage x tile 32x32 (256 float4, 1/thread)
      int r = t >> 3, c4 = t & 7;
      float4 v = *(const float4*)(x + (size_t)(m0 + r) * En + k0 + c4 * 4);
      *(float4*)&xs[r][c4 * 4] = v;
    }
    #pragma unroll
    for (int i = 0; i < 2; ++i) { // stage w tile 32x64 (512 float4, 2/thread)
      int fidx = i * 256 + t;
      int kr = fidx >> 4, c4 = fidx & 15;
      float4 v = *(const float4*)(w + (size_t)(k0 + kr) * Hn + n0 + c4 * 4);
      *(float4*)&ws[kr][c4 * 4] = v;
    }
    __syncthreads();
    #pragma unroll
    for (int kk = 0; kk < 32; ++kk) {
      float a0 = xs[mr][kk];
      float a1 = xs[mr + 1][kk];
      float4 wv = *(const float4*)&ws[kk][nc];
      acc0 = f4_fma(a0, wv, acc0);
      acc1 = f4_fma(a1, wv, acc1);
    }
    __syncthreads();
  }

  const float s0 = rs[m0 + mr], s1 = rs[m0 + mr + 1];
  const float4 bv = *(const float4*)(bias + n0 + nc);
  float4 o0, o1;
  o0.x = acc0.x * s0 + bv.x; o0.y = acc0.y * s0 + bv.y;
  o0.z = acc0.z * s0 + bv.z; o0.w = acc0.w * s0 + bv.w;
  o1.x = acc1.x * s1 + bv.x; o1.y = acc1.y * s1 + bv.y;
  o1.z = acc1.z * s1 + bv.z; o1.w = acc1.w * s1 + bv.w;
  *(float4*)(outp + (size_t)(m0 + mr)     * Hn + n0 + nc) = o0;
  *(float4*)(outp + (size_t)(m0 + mr + 1) * Hn + n0 + nc) = o1;
}

// ---------------------------------------------------------------------------
// K2: in-place RMSNorm of 2048 rows (A then Bm, contiguous). Wave per row.
// ---------------------------------------------------------------------------
__global__ __launch_bounds__(256) void k_norm(float* __restrict__ AB)
{
  const int row  = blockIdx.x * 4 + (threadIdx.x >> 6);
  const int lane = threadIdx.x & 63;
  float4* p = (float4*)(AB + (size_t)row * Hn);
  float4 v = p[lane];
  float ss = v.x*v.x + v.y*v.y + v.z*v.z + v.w*v.w;
  #pragma unroll
  for (int off = 32; off > 0; off >>= 1) ss += __shfl_xor(ss, off, 64);
  const float sc = rsqrtf(ss * (1.0f / Hn) + EPSF);
  v.x *= sc; v.y *= sc; v.z *= sc; v.w *= sc;
  p[lane] = v;
}

// ---------------------------------------------------------------------------
// K3: causal relu prefix + fused RMSNorm (exact: y = S * rsqrt(mean(S^2)+eps*c^2))
// ITILE=4 rows/block, thread = h. Double-buffered 16-deep register prefetch.
// ---------------------------------------------------------------------------
#define ITILE 4
#define JCH   16
__global__ __launch_bounds__(256) void k_bar(
    const float* __restrict__ A, const float* __restrict__ Bm,
    float* __restrict__ Y)
{
  const int tile = blockIdx.x & 127;
  const int bb   = blockIdx.x >> 7;
  const int i0   = tile * ITILE;
  const int h    = threadIdx.x;
  const size_t base = (size_t)bb * Tn * Hn;
  const float* __restrict__ bp = Bm + base + h;

  float av[ITILE], sum[ITILE];
  #pragma unroll
  for (int r = 0; r < ITILE; ++r) {
    av[r]  = A[base + (size_t)(i0 + r) * Hn + h];
    sum[r] = 0.f;
  }

  const int nfull = i0 & ~(JCH - 1);   // j in [0,nfull) via full 16-chunks
  float b0[JCH], b1[JCH];

  #define LOADCH(buf, jj) { _Pragma("unroll") \
    for (int tt = 0; tt < JCH; ++tt) buf[tt] = bp[(size_t)((jj) + tt) * Hn]; }
  #define COMPCH(buf) { _Pragma("unroll") \
    for (int tt = 0; tt < JCH; ++tt) { float bv = buf[tt]; _Pragma("unroll") \
      for (int r = 0; r < ITILE; ++r) sum[r] += fmaxf(av[r] + bv, 0.f); } }

  if (nfull > 0) {
    LOADCH(b0, 0);
    int j = 0;
    while (true) {
      const bool more1 = (j + JCH     < nfull);
      const bool more2 = (j + 2 * JCH < nfull);
      if (more1) LOADCH(b1, j + JCH);
      COMPCH(b0);
      j += JCH;
      if (!more1) break;
      if (more2) LOADCH(b0, j + JCH);
      COMPCH(b1);
      j += JCH;
      if (!more2) break;
    }
  }

  // fixed-width predicated tail: j in [nfull, i0+ITILE), i0-nfull in {0,4,8,12}
  {
    float bt[JCH];
    LOADCH(bt, nfull);                 // max j = nfull+15 <= 511, in-bounds
    const int lim = i0 - nfull;        // row r active iff tt <= lim + r
    #pragma unroll
    for (int tt = 0; tt < JCH; ++tt) {
      float bv = bt[tt];
      #pragma unroll
      for (int r = 0; r < ITILE; ++r)
        sum[r] += (tt <= lim + r) ? fmaxf(av[r] + bv, 0.f) : 0.f;
    }
  }
  #undef LOADCH
  #undef COMPCH

  __shared__ float red[4];
  #pragma unroll
  for (int r = 0; r < ITILE; ++r) {
    float ss = block_reduce_sum_256(sum[r] * sum[r], red);
    float c  = (float)(i0 + r + 1);
    float sc = rsqrtf(ss * (1.0f / Hn) + EPSF * c * c);
    Y[base + (size_t)(i0 + r) * Hn + h] = sum[r] * sc;
  }
}

// ---------------------------------------------------------------------------
// K4: out = x + Ynorm @ w3 + b3. LDS-tiled: BM=64, BN=64, BK=64, micro 4x4.
// grid: 16 mtiles * 16 ntiles = 256 blocks.
// ---------------------------------------------------------------------------
__global__ __launch_bounds__(256) void k_out(
    const float* __restrict__ Y,
    const float* __restrict__ w3, const float* __restrict__ b3,
    const float* __restrict__ x, float* __restrict__ out)
{
  const int bx = blockIdx.x;
  const int nt = bx & 15;
  const int mt = bx >> 4;
  const int m0 = mt * 64, n0 = nt * 64;

  __shared__ float yt[64][68];   // +4 pad
  __shared__ float wt[64][64];

  const int t  = threadIdx.x;
  const int mr = (t >> 4) * 4;
  const int nc = (t & 15) * 4;

  float4 acc[4];
  #pragma unroll
  for (int i = 0; i < 4; ++i) acc[i] = make_float4(0,0,0,0);

  for (int k0 = 0; k0 < Hn; k0 += 64) {
    #pragma unroll
    for (int i = 0; i < 4; ++i) {   // stage Y tile 64x64
      int fidx = i * 256 + t;
      int r = fidx >> 4, c4 = fidx & 15;
      float4 v = *(const float4*)(Y + (size_t)(m0 + r) * Hn + k0 + c4 * 4);
      *(float4*)&yt[r][c4 * 4] = v;
    }
    #pragma unroll
    for (int i = 0; i < 4; ++i) {   // stage w3 tile 64x64
      int fidx = i * 256 + t;
      int r = fidx >> 4, c4 = fidx & 15;
      float4 v = *(const float4*)(w3 + (size_t)(k0 + r) * En + n0 + c4 * 4);
      *(float4*)&wt[r][c4 * 4] = v;
    }
    __syncthreads();
    #pragma unroll
    for (int kk = 0; kk < 64; ++kk) {
      float4 wv = *(const float4*)&wt[kk][nc];
      #pragma unroll
      for (int i = 0; i < 4; ++i)
        acc[i] = f4_fma(yt[mr + i][kk], wv, acc[i]);
    }
    __syncthreads();
  }

  const float4 bv = *(const float4*)(b3 + n0 + nc);
  #pragma unroll
  for (int i = 0; i < 4; ++i) {
    const float4 xv = *(const float4*)(x + (size_t)(m0 + mr + i) * En + n0 + nc);
    float4 o;
    o.x = xv.x + acc[i].x + bv.x;
    o.y = xv.y + acc[i].y + bv.y;
    o.z = xv.z + acc[i].z + bv.z;
    o.w = xv.w + acc[i].w + bv.w;
    *(float4*)(out + (size_t)(m0 + mr + i) * En + n0 + nc) = o;
  }
}

// ---------------------------------------------------------------------------
extern "C" void kernel_launch(void* const* d_in, const int* in_sizes, int n_in,
                              void* d_out, int out_size, void* d_ws, size_t ws_size,
                              hipStream_t stream) {
  const float* x  = (const float*)d_in[0];
  const float* w1 = (const float*)d_in[1];
  const float* b1 = (const float*)d_in[2];
  const float* w2 = (const float*)d_in[3];
  const float* b2 = (const float*)d_in[4];
  const float* w3 = (const float*)d_in[5];
  const float* b3 = (const float*)d_in[6];
  float* out = (float*)d_out;

  float* A  = (float*)d_ws;                        // [Mtot, Hn]
  float* Bm = A  + (size_t)Mtot * Hn;              // [Mtot, Hn]
  float* Y  = Bm + (size_t)Mtot * Hn;              // [Mtot, Hn]
  float* rs = Y  + (size_t)Mtot * Hn;              // [Mtot]

  k_rowscale<<<Mtot / 4, 256, 0, stream>>>(x, rs);
  k_gemm_ab <<<256,      256, 0, stream>>>(x, w1, b1, w2, b2, rs, A, Bm);
  k_norm    <<<2 * Mtot / 4, 256, 0, stream>>>(A);   // A and Bm contiguous
  k_bar     <<<Bsz * (Tn / ITILE), 256, 0, stream>>>(A, Bm, Y);
  k_out     <<<256,      256, 0, stream>>>(Y, w3, b3, x, out);
}

// Round 3
// 53.298 us; speedup vs baseline: 3.8433x; 1.4702x over previous
//
#include <hip/hip_runtime.h>

#define EPSF 1e-6f
#define Bsz 2
#define Tn  512
#define En  1024
#define Hn  256
#define Mtot (Bsz * Tn)          // 1024 rows
typedef unsigned short us_t;
typedef unsigned int   u32_t;

typedef __attribute__((ext_vector_type(8))) short bf16x8;
typedef __attribute__((ext_vector_type(4))) float f32x4;
#define MFMA16(a, b, c) __builtin_amdgcn_mfma_f32_16x16x32_bf16((a), (b), (c), 0, 0, 0)

// ---------------------------------------------------------------------------
__device__ __forceinline__ us_t f2bf(float f) {
  union { float f; u32_t u; } x; x.f = f;
  u32_t r = (x.u + 0x7fffu + ((x.u >> 16) & 1u)) >> 16;   // RNE
  return (us_t)r;
}
__device__ __forceinline__ float bf2f(us_t u) {
  union { u32_t u; float f; } x; x.u = ((u32_t)u) << 16; return x.f;
}
__device__ __forceinline__ uint2 pack4bf(float a, float b, float c, float d) {
  uint2 r;
  r.x = (u32_t)f2bf(a) | ((u32_t)f2bf(b) << 16);
  r.y = (u32_t)f2bf(c) | ((u32_t)f2bf(d) << 16);
  return r;
}
__device__ __forceinline__ float block_reduce_sum_256(float v, float* smem) {
  #pragma unroll
  for (int off = 32; off > 0; off >>= 1) v += __shfl_down(v, off, 64);
  const int wave = threadIdx.x >> 6;
  if ((threadIdx.x & 63) == 0) smem[wave] = v;
  __syncthreads();
  float s = smem[0] + smem[1] + smem[2] + smem[3];
  __syncthreads();
  return s;
}

// ---------------------------------------------------------------------------
// K0: xb = bf16(x); rs[row] = rsqrt(mean(x_row^2)+eps).  Block per row.
// ---------------------------------------------------------------------------
__global__ __launch_bounds__(256) void k_castx_rs(
    const float* __restrict__ x, us_t* __restrict__ xb, float* __restrict__ rs)
{
  __shared__ float red[4];
  const int row = blockIdx.x, t = threadIdx.x;
  float4 v = ((const float4*)(x + (size_t)row * En))[t];
  float ss = block_reduce_sum_256(v.x*v.x + v.y*v.y + v.z*v.z + v.w*v.w, red);
  if (t == 0) rs[row] = rsqrtf(ss * (1.0f / En) + EPSF);
  ((uint2*)(xb + (size_t)row * En))[t] = pack4bf(v.x, v.y, v.z, v.w);
}

// ---------------------------------------------------------------------------
// K1: transpose+cast w1,w2 (1024x256 -> [256][1024] bf16) and w3
// (256x1024 -> [1024][256] bf16).  32x32 LDS tiles; 768 blocks.
// ---------------------------------------------------------------------------
__global__ __launch_bounds__(256) void k_tr(
    const float* __restrict__ w1, const float* __restrict__ w2,
    const float* __restrict__ w3,
    us_t* __restrict__ w1t, us_t* __restrict__ w2t, us_t* __restrict__ w3t)
{
  const int b = blockIdx.x, t = threadIdx.x;
  const float* src; us_t* dst; int R, C, tr, tc;
  if (b < 256)      { src = w1; dst = w1t; R = 1024; C = 256;  tr = b >> 3;  tc = b & 7; }
  else if (b < 512) { int i = b - 256; src = w2; dst = w2t; R = 1024; C = 256; tr = i >> 3; tc = i & 7; }
  else              { int i = b - 512; src = w3; dst = w3t; R = 256; C = 1024; tr = i >> 5; tc = i & 31; }

  __shared__ float ts[32][33];
  const int r = t >> 3, c4 = (t & 7) * 4;
  float4 v = *(const float4*)(src + (size_t)(tr * 32 + r) * C + tc * 32 + c4);
  ts[r][c4 + 0] = v.x; ts[r][c4 + 1] = v.y; ts[r][c4 + 2] = v.z; ts[r][c4 + 3] = v.w;
  __syncthreads();
  float o0 = ts[c4 + 0][r], o1 = ts[c4 + 1][r], o2 = ts[c4 + 2][r], o3 = ts[c4 + 3][r];
  *(uint2*)(dst + (size_t)(tc * 32 + r) * R + tr * 32 + c4) = pack4bf(o0, o1, o2, o3);
}

// ---------------------------------------------------------------------------
// K2: MFMA GEMM for a/b, LDS-free.  Wave tile 32x32, K-split x4 (K-slice 256).
// A-frags direct from xb [M][K] rows; B-frags from w1t/w2t [N][K] rows.
// Raw dot partials (no rs/bias) -> P[ks][1024][512] f32.
// 512 blocks x 4 waves = 2048 waves = 32 mt x 16 nt x 4 ks.
// ---------------------------------------------------------------------------
__global__ __launch_bounds__(256) void k_gemm_ab(
    const us_t* __restrict__ xb,
    const us_t* __restrict__ w1t, const us_t* __restrict__ w2t,
    float* __restrict__ P)
{
  const int wid = threadIdx.x >> 6, lane = threadIdx.x & 63;
  const int wg = blockIdx.x * 4 + wid;
  const int ks = wg & 3, nt = (wg >> 2) & 15, mt = wg >> 6;
  const int m0 = mt * 32, n0 = nt * 32, k0 = ks * 256;
  const int lg = lane >> 4, lr = lane & 15;

  const us_t* ap0 = xb + (size_t)(m0 + lr) * En + k0 + lg * 8;
  const us_t* ap1 = ap0 + 16 * En;
  const us_t* bbase = (n0 < Hn) ? (w1t + (size_t)n0 * En) : (w2t + (size_t)(n0 - Hn) * En);
  const us_t* bp0 = bbase + (size_t)lr * En + k0 + lg * 8;
  const us_t* bp1 = bp0 + 16 * En;

  f32x4 acc00 = {0.f,0.f,0.f,0.f}, acc01 = acc00, acc10 = acc00, acc11 = acc00;

  #pragma unroll 4
  for (int s = 0; s < 8; ++s) {
    bf16x8 a0 = *(const bf16x8*)(ap0 + s * 32);
    bf16x8 a1 = *(const bf16x8*)(ap1 + s * 32);
    bf16x8 b0 = *(const bf16x8*)(bp0 + s * 32);
    bf16x8 b1 = *(const bf16x8*)(bp1 + s * 32);
    acc00 = MFMA16(a0, b0, acc00);
    acc01 = MFMA16(a0, b1, acc01);
    acc10 = MFMA16(a1, b0, acc10);
    acc11 = MFMA16(a1, b1, acc11);
  }

  // C/D layout: col = lane&15, row = (lane>>4)*4 + reg   [HW-verified]
  float* pw = P + ((size_t)ks * Mtot + m0 + lg * 4) * 512 + n0 + lr;
  #pragma unroll
  for (int i = 0; i < 4; ++i) {
    pw[(size_t)i        * 512      ] = acc00[i];
    pw[(size_t)i        * 512 + 16 ] = acc01[i];
    pw[(size_t)(i + 16) * 512      ] = acc10[i];
    pw[(size_t)(i + 16) * 512 + 16 ] = acc11[i];
  }
}

// ---------------------------------------------------------------------------
// K3: combine 4 K-partials, apply rs & bias, RMS-norm row, write a/b bf16.
// Wave per row; 2048 rows (which 0 -> A, 1 -> Bm). 512 blocks.
// ---------------------------------------------------------------------------
__global__ __launch_bounds__(256) void k_norm(
    const float* __restrict__ P, const float* __restrict__ rs,
    const float* __restrict__ b1, const float* __restrict__ b2,
    us_t* __restrict__ A, us_t* __restrict__ Bm)
{
  const int rw = blockIdx.x * 4 + (threadIdx.x >> 6);
  const int lane = threadIdx.x & 63;
  const int which = rw >> 10, r = rw & 1023;
  const float* bias = which ? b2 : b1;
  const int h0 = lane * 4;
  const size_t off = (size_t)r * 512 + which * Hn + h0;
  const size_t KS = (size_t)Mtot * 512;

  float4 d0 = *(const float4*)(P + off);
  float4 d1 = *(const float4*)(P + off + KS);
  float4 d2 = *(const float4*)(P + off + 2 * KS);
  float4 d3 = *(const float4*)(P + off + 3 * KS);
  const float sc0 = rs[r];
  float4 bv = *(const float4*)(bias + h0);
  float vx = (d0.x + d1.x + d2.x + d3.x) * sc0 + bv.x;
  float vy = (d0.y + d1.y + d2.y + d3.y) * sc0 + bv.y;
  float vz = (d0.z + d1.z + d2.z + d3.z) * sc0 + bv.z;
  float vw = (d0.w + d1.w + d2.w + d3.w) * sc0 + bv.w;

  float ss = vx*vx + vy*vy + vz*vz + vw*vw;
  #pragma unroll
  for (int off2 = 32; off2 > 0; off2 >>= 1) ss += __shfl_xor(ss, off2, 64);
  const float sc = rsqrtf(ss * (1.0f / Hn) + EPSF);

  us_t* outp = which ? Bm : A;
  *(uint2*)(outp + (size_t)r * Hn + h0) = pack4bf(vx * sc, vy * sc, vz * sc, vw * sc);
}

// ---------------------------------------------------------------------------
// K4: causal relu prefix + fused RMSNorm.  ITILE=2 -> 512 blocks (2/CU).
// a/b read as bf16 (halves L2 draw); Y written bf16 for the MFMA out-GEMM.
// ---------------------------------------------------------------------------
#define ITILE 2
#define JCH   16
__global__ __launch_bounds__(256) void k_bar(
    const us_t* __restrict__ A, const us_t* __restrict__ Bm,
    us_t* __restrict__ Yb)
{
  const int tile = blockIdx.x & 255;
  const int bb   = blockIdx.x >> 8;
  const int i0   = tile * ITILE;
  const int h    = threadIdx.x;
  const size_t base = (size_t)bb * Tn * Hn;
  const us_t* __restrict__ bp = Bm + base + h;

  float av[ITILE], sum[ITILE];
  #pragma unroll
  for (int r = 0; r < ITILE; ++r) {
    av[r]  = bf2f(A[base + (size_t)(i0 + r) * Hn + h]);
    sum[r] = 0.f;
  }

  const int nfull = i0 & ~(JCH - 1);
  us_t b0[JCH], b1[JCH];

  #define LOADCH(buf, jj) { _Pragma("unroll") \
    for (int tt = 0; tt < JCH; ++tt) buf[tt] = bp[(size_t)((jj) + tt) * Hn]; }
  #define COMPCH(buf) { _Pragma("unroll") \
    for (int tt = 0; tt < JCH; ++tt) { float bv = bf2f(buf[tt]); _Pragma("unroll") \
      for (int r = 0; r < ITILE; ++r) sum[r] += fmaxf(av[r] + bv, 0.f); } }

  if (nfull > 0) {
    LOADCH(b0, 0);
    int j = 0;
    while (true) {
      const bool more1 = (j + JCH     < nfull);
      const bool more2 = (j + 2 * JCH < nfull);
      if (more1) LOADCH(b1, j + JCH);
      COMPCH(b0);
      j += JCH;
      if (!more1) break;
      if (more2) LOADCH(b0, j + JCH);
      COMPCH(b1);
      j += JCH;
      if (!more2) break;
    }
  }
  { // fixed-width predicated tail (loads stay in-bounds: nfull+15 <= 511)
    us_t bt[JCH];
    LOADCH(bt, nfull);
    const int lim = i0 - nfull;
    #pragma unroll
    for (int tt = 0; tt < JCH; ++tt) {
      float bv = bf2f(bt[tt]);
      #pragma unroll
      for (int r = 0; r < ITILE; ++r)
        sum[r] += (tt <= lim + r) ? fmaxf(av[r] + bv, 0.f) : 0.f;
    }
  }
  #undef LOADCH
  #undef COMPCH

  __shared__ float red[4];
  #pragma unroll
  for (int r = 0; r < ITILE; ++r) {
    float ss = block_reduce_sum_256(sum[r] * sum[r], red);
    float c  = (float)(i0 + r + 1);
    float sc = rsqrtf(ss * (1.0f / Hn) + EPSF * c * c);
    Yb[base + (size_t)(i0 + r) * Hn + h] = f2bf(sum[r] * sc);
  }
}

// ---------------------------------------------------------------------------
// K5: out = x + Ynorm @ w3 + b3.  MFMA, LDS-free.  Wave tile 16x32, K=256.
// 512 blocks x 4 waves = 2048 waves = 64 mt x 32 nt.
// ---------------------------------------------------------------------------
__global__ __launch_bounds__(256) void k_out(
    const us_t* __restrict__ Yb, const us_t* __restrict__ w3t,
    const float* __restrict__ x, const float* __restrict__ b3,
    float* __restrict__ out)
{
  const int wid = threadIdx.x >> 6, lane = threadIdx.x & 63;
  const int wg = blockIdx.x * 4 + wid;
  const int nt = wg & 31, mt = wg >> 5;
  const int m0 = mt * 16, n0 = nt * 32;
  const int lg = lane >> 4, lr = lane & 15;

  const us_t* ap  = Yb  + (size_t)(m0 + lr) * Hn + lg * 8;
  const us_t* bp0 = w3t + (size_t)(n0 + lr) * Hn + lg * 8;
  const us_t* bp1 = bp0 + 16 * Hn;

  f32x4 acc0 = {0.f,0.f,0.f,0.f}, acc1 = acc0;

  #pragma unroll 4
  for (int s = 0; s < 8; ++s) {
    bf16x8 a  = *(const bf16x8*)(ap  + s * 32);
    bf16x8 b0 = *(const bf16x8*)(bp0 + s * 32);
    bf16x8 b1 = *(const bf16x8*)(bp1 + s * 32);
    acc0 = MFMA16(a, b0, acc0);
    acc1 = MFMA16(a, b1, acc1);
  }

  const int row = m0 + lg * 4;
  const int c0 = n0 + lr, c1 = n0 + 16 + lr;
  const float bv0 = b3[c0], bv1 = b3[c1];
  #pragma unroll
  for (int i = 0; i < 4; ++i) {
    const size_t o0 = (size_t)(row + i) * En + c0;
    const size_t o1 = (size_t)(row + i) * En + c1;
    out[o0] = x[o0] + acc0[i] + bv0;
    out[o1] = x[o1] + acc1[i] + bv1;
  }
}

// ---------------------------------------------------------------------------
extern "C" void kernel_launch(void* const* d_in, const int* in_sizes, int n_in,
                              void* d_out, int out_size, void* d_ws, size_t ws_size,
                              hipStream_t stream) {
  const float* x  = (const float*)d_in[0];
  const float* w1 = (const float*)d_in[1];
  const float* b1 = (const float*)d_in[2];
  const float* w2 = (const float*)d_in[3];
  const float* b2 = (const float*)d_in[4];
  const float* w3 = (const float*)d_in[5];
  const float* b3 = (const float*)d_in[6];
  float* out = (float*)d_out;

  char* p = (char*)d_ws;
  float* P   = (float*)p;               p += (size_t)4 * Mtot * 512 * 4;  // 8 MB
  us_t* xb   = (us_t*)p;                p += (size_t)Mtot * En * 2;       // 2 MB
  us_t* w1t  = (us_t*)p;                p += (size_t)Hn * En * 2;
  us_t* w2t  = (us_t*)p;                p += (size_t)Hn * En * 2;
  us_t* w3t  = (us_t*)p;                p += (size_t)En * Hn * 2;
  us_t* A    = (us_t*)p;                p += (size_t)Mtot * Hn * 2;
  us_t* Bm   = (us_t*)p;                p += (size_t)Mtot * Hn * 2;
  us_t* Yb   = (us_t*)p;                p += (size_t)Mtot * Hn * 2;
  float* rs  = (float*)p;               p += (size_t)Mtot * 4;

  k_castx_rs<<<Mtot, 256, 0, stream>>>(x, xb, rs);
  k_tr      <<<768,  256, 0, stream>>>(w1, w2, w3, w1t, w2t, w3t);
  k_gemm_ab <<<512,  256, 0, stream>>>(xb, w1t, w2t, P);
  k_norm    <<<512,  256, 0, stream>>>(P, rs, b1, b2, A, Bm);
  k_bar     <<<Bsz * (Tn / ITILE), 256, 0, stream>>>(A, Bm, Yb);
  k_out     <<<512,  256, 0, stream>>>(Yb, w3t, x, b3, out);
}